// Round 3
// baseline (679.685 us; speedup 1.0000x reference)
//
#include <hip/hip_runtime.h>
#include <hip/hip_bf16.h>
#include <math.h>

#define T_TOK 2048
#define D_DIM 1024
#define F_DIM 4096
#define E_NUM 8

typedef __attribute__((ext_vector_type(8))) short short8;
typedef __attribute__((ext_vector_type(4))) short short4v;
typedef __attribute__((ext_vector_type(4))) float floatx4;

__device__ __forceinline__ short f2bf(float f) {
  union { float f; unsigned u; } v; v.f = f;
  unsigned r = v.u + 0x7fffu + ((v.u >> 16) & 1u);  // RNE
  return (short)(r >> 16);
}

// async global->LDS, 16B per lane. LDS base must be wave-uniform; data for
// lane l lands at lds + l*16 bytes.
__device__ __forceinline__ void gld_lds16(const void* g, void* l) {
  __builtin_amdgcn_global_load_lds(
      (const __attribute__((address_space(1))) unsigned int*)g,
      (__attribute__((address_space(3))) unsigned int*)l, 16, 0, 0);
}

// ---------------- Router (fp32): logits, top-2, renorm, expert slot lists ----------------
__global__ __launch_bounds__(256) void router_kernel(
    const float* __restrict__ x, const float* __restrict__ wr,
    int* __restrict__ counts, int* __restrict__ slot_sid, float* __restrict__ slot_w) {
  int lane = threadIdx.x & 63;
  int wave = threadIdx.x >> 6;
  int t = blockIdx.x * 4 + wave;
  const float* xr = x + (size_t)t * D_DIM;
  float acc[8];
#pragma unroll
  for (int e = 0; e < 8; e++) acc[e] = 0.f;
#pragma unroll
  for (int i = 0; i < 16; i++) {
    int d = i * 64 + lane;
    float xv = xr[d];
    const float* w = wr + d * 8;
    float4 w0 = *(const float4*)(w);
    float4 w1 = *(const float4*)(w + 4);
    acc[0] += xv * w0.x; acc[1] += xv * w0.y;
    acc[2] += xv * w0.z; acc[3] += xv * w0.w;
    acc[4] += xv * w1.x; acc[5] += xv * w1.y;
    acc[6] += xv * w1.z; acc[7] += xv * w1.w;
  }
#pragma unroll
  for (int off = 32; off > 0; off >>= 1) {
#pragma unroll
    for (int e = 0; e < 8; e++) acc[e] += __shfl_xor(acc[e], off, 64);
  }
  if (lane == 0) {
    int e1 = 0; float l1 = acc[0];
#pragma unroll
    for (int e = 1; e < 8; e++) { if (acc[e] > l1) { l1 = acc[e]; e1 = e; } }
    int e2 = -1; float l2 = -3.4e38f;
#pragma unroll
    for (int e = 0; e < 8; e++) { if (e != e1 && acc[e] > l2) { l2 = acc[e]; e2 = e; } }
    float w1 = 1.f / (1.f + __expf(l2 - l1));  // softmax->top2->renorm
    float w2 = 1.f - w1;
    int p1 = atomicAdd(&counts[e1], 1);
    slot_sid[e1 * T_TOK + p1] = 2 * t;
    slot_w[e1 * T_TOK + p1] = w1;
    int p2 = atomicAdd(&counts[e2], 1);
    slot_sid[e2 * T_TOK + p2] = 2 * t + 1;
    slot_w[e2 * T_TOK + p2] = w2;
  }
}

// ---------------- x fp32 -> bf16 ----------------
__global__ __launch_bounds__(256) void cvt_x_kernel(const float* __restrict__ x,
                                                    short* __restrict__ Xb) {
  int i = blockIdx.x * 256 + threadIdx.x;   // float4 index
  float4 v = ((const float4*)x)[i];
  short4v s;
  s[0] = f2bf(v.x); s[1] = f2bf(v.y); s[2] = f2bf(v.z); s[3] = f2bf(v.w);
  ((short4v*)Xb)[i] = s;
}

// ---------------- Transpose+convert: src fp32 [R][C] -> dst bf16 [C][R] per plane ----------------
__global__ __launch_bounds__(256) void transpose_cvt_kernel(
    const float* __restrict__ src, short* __restrict__ dst, int R, int C) {
  __shared__ short tile[64][68];
  int cb = blockIdx.x * 64, rb = blockIdx.y * 64;
  size_t plane = (size_t)blockIdx.z * R * C;
  src += plane; dst += plane;
  int tid = threadIdx.x;
  int r0 = tid >> 4, c4 = (tid & 15) * 4;
#pragma unroll
  for (int i = 0; i < 4; i++) {
    int r = r0 + i * 16;
    float4 v = *(const float4*)&src[(size_t)(rb + r) * C + cb + c4];
    short4v s;
    s[0] = f2bf(v.x); s[1] = f2bf(v.y); s[2] = f2bf(v.z); s[3] = f2bf(v.w);
    *(short4v*)&tile[r][c4] = s;
  }
  __syncthreads();
  int c0 = tid >> 4, r4 = (tid & 15) * 4;
#pragma unroll
  for (int i = 0; i < 4; i++) {
    int c = c0 + i * 16;
    short4v s;
    s[0] = tile[r4][c]; s[1] = tile[r4 + 1][c];
    s[2] = tile[r4 + 2][c]; s[3] = tile[r4 + 3][c];
    *(short4v*)&dst[(size_t)(cb + c) * R + rb + r4] = s;
  }
}

// ---------------- Fused gate+up GEMM: tile 128x64, BK=32, single-buffer ----------------
// R3 restructure for TLP: N-tile 64 (acc halves to 64 AGPR -> 3 waves/SIMD
// resident vs 2 at N=128), and mt OUTERMOST across experts so live blocks
// (mt < ceil(n_e/128), n_e ~= 512) are one contiguous bid range -> uniform
// CU/XCD fill. 2-phase dbuf reverted (R2: neutral; costs LDS).
// bid = mt*512 + e*64 + nt;  grid 16*8*64 = 8192, ~2048 live.
__global__ __launch_bounds__(256, 3) void gateup_kernel(
    const short* __restrict__ Xb, const short* __restrict__ WgT, const short* __restrict__ WuT,
    const int* __restrict__ counts, const int* __restrict__ slot_sid,
    short* __restrict__ H) {
  __shared__ short smem[8192];         // As 128x32 (4K shorts) | Bg 64x32 (2K) | Bu 64x32 (2K)
  __shared__ int s_sid[128];

  int bid = blockIdx.x;
  int mt = bid >> 9;
  int e  = (bid >> 6) & 7;
  int nt = bid & 63;
  int n_e = counts[e];
  if (mt * 128 >= n_e) return;

  int tid = threadIdx.x;
  if (tid < 128) {
    int i = mt * 128 + tid;
    if (i > n_e - 1) i = n_e - 1;      // clamp; guarded at store
    s_sid[tid] = slot_sid[e * T_TOK + i];
  }
  __syncthreads();

  int lane = tid & 63;
  int w = tid >> 6;
  int wm = w >> 1, wn = w & 1;
  int r16 = lane & 15, q = lane >> 4;

  // staging: A rows in 2 chunks of 16/wave (rows w*16+r, 64+w*16+r); B rows w*16+r
  int rl = lane >> 2;                  // row within 16-chunk
  int kc = (lane & 3) * 8;             // shorts within 32-k row
  const short* aP0 = Xb + (size_t)(s_sid[w * 16 + rl] >> 1) * D_DIM + kc;
  const short* aP1 = Xb + (size_t)(s_sid[64 + w * 16 + rl] >> 1) * D_DIM + kc;
  size_t wbase = (size_t)e * F_DIM * D_DIM + (size_t)(nt * 64 + w * 16 + rl) * D_DIM;
  const short* gP = WgT + wbase + kc;
  const short* uP = WuT + wbase + kc;
  short* ldsA0 = smem + w * 512;               // rows [w*16,w*16+16)
  short* ldsA1 = smem + 2048 + w * 512;        // rows [64+w*16, ...)
  short* ldsBg = smem + 4096 + w * 512;
  short* ldsBu = smem + 6144 + w * 512;

  floatx4 zero4 = {0.f, 0.f, 0.f, 0.f};
  floatx4 accg[4][2], accu[4][2];
#pragma unroll
  for (int a = 0; a < 4; a++)
#pragma unroll
    for (int b = 0; b < 2; b++) { accg[a][b] = zero4; accu[a][b] = zero4; }

  for (int kb = 0; kb < D_DIM / 32; kb++) {
    gld_lds16(aP0, ldsA0);
    gld_lds16(aP1, ldsA1);
    gld_lds16(gP, ldsBg);
    gld_lds16(uP, ldsBu);
    aP0 += 32; aP1 += 32; gP += 32; uP += 32;
    __syncthreads();
    const short* As = smem;
    const short* Bg = smem + 4096;
    const short* Bu = smem + 6144;
    short8 af[4], bgf[2], buf_[2];
#pragma unroll
    for (int f = 0; f < 4; f++)
      af[f] = *(const short8*)&As[(wm * 64 + f * 16 + r16) * 32 + q * 8];
#pragma unroll
    for (int f = 0; f < 2; f++) {
      bgf[f]  = *(const short8*)&Bg[(wn * 32 + f * 16 + r16) * 32 + q * 8];
      buf_[f] = *(const short8*)&Bu[(wn * 32 + f * 16 + r16) * 32 + q * 8];
    }
#pragma unroll
    for (int fm = 0; fm < 4; fm++)
#pragma unroll
      for (int fn = 0; fn < 2; fn++) {
        accg[fm][fn] = __builtin_amdgcn_mfma_f32_16x16x32_bf16(af[fm], bgf[fn],  accg[fm][fn], 0, 0, 0);
        accu[fm][fn] = __builtin_amdgcn_mfma_f32_16x16x32_bf16(af[fm], buf_[fn], accu[fm][fn], 0, 0, 0);
      }
    __syncthreads();
  }

  // epilogue via LDS slab (stride 72 shorts = 144B, 16B-aligned rows) -> 16B stores
  short* slab = smem;
#pragma unroll
  for (int fm = 0; fm < 4; fm++) {
#pragma unroll
    for (int reg = 0; reg < 4; reg++) {
      int rowl = wm * 16 + q * 4 + reg;
#pragma unroll
      for (int fn = 0; fn < 2; fn++) {
        float g = accg[fm][fn][reg];
        float u = accu[fm][fn][reg];
        float h = g * u / (1.f + __expf(-g));
        slab[rowl * 72 + wn * 32 + fn * 16 + r16] = f2bf(h);
      }
    }
    __syncthreads();
    int rr = tid >> 3, cs = (tid & 7) * 8;     // 32 rows x 64 shorts, 16B/thread
    int grow = (rr >> 4) * 64 + fm * 16 + (rr & 15);
    if (mt * 128 + grow < n_e) {
      int sid = s_sid[grow];
      short8 v0 = *(const short8*)&slab[rr * 72 + cs];
      *(short8*)(H + (size_t)sid * F_DIM + nt * 64 + cs) = v0;
    }
    __syncthreads();
  }
}

// ---------------- Down GEMM, split-K=4: tile 128x64, BK=32, single-buffer ----------------
// bid = mt*512 + e*64 + sk*16 + nt;  grid 16*8*4*16 = 8192, ~2048 live.
__global__ __launch_bounds__(256, 3) void down_kernel(
    const short* __restrict__ H, const short* __restrict__ WdT,
    const int* __restrict__ counts, const int* __restrict__ slot_sid,
    const float* __restrict__ slot_w, float* __restrict__ Y) {
  __shared__ short smem[6144];         // As 128x32 (4K shorts) | Bs 64x32 (2K)
  __shared__ int s_sid[128];
  __shared__ float s_w[128];

  int bid = blockIdx.x;
  int mt = bid >> 9;
  int e  = (bid >> 6) & 7;
  int sk = (bid >> 4) & 3;
  int nt = bid & 15;
  int n_e = counts[e];
  if (mt * 128 >= n_e) return;

  int tid = threadIdx.x;
  if (tid < 128) {
    int i = mt * 128 + tid;
    if (i > n_e - 1) i = n_e - 1;
    s_sid[tid] = slot_sid[e * T_TOK + i];
    s_w[tid]   = slot_w[e * T_TOK + i];
  }
  __syncthreads();

  int lane = tid & 63;
  int w = tid >> 6;
  int wm = w >> 1, wn = w & 1;
  int r16 = lane & 15, q = lane >> 4;

  int rl = lane >> 2;
  int kc = (lane & 3) * 8;
  int ks = sk * (F_DIM / 4);
  const short* aP0 = H + (size_t)s_sid[w * 16 + rl] * F_DIM + ks + kc;
  const short* aP1 = H + (size_t)s_sid[64 + w * 16 + rl] * F_DIM + ks + kc;
  const short* bP = WdT + ((size_t)e * D_DIM + nt * 64 + w * 16 + rl) * F_DIM + ks + kc;
  short* ldsA0 = smem + w * 512;
  short* ldsA1 = smem + 2048 + w * 512;
  short* ldsB  = smem + 4096 + w * 512;

  floatx4 zero4 = {0.f, 0.f, 0.f, 0.f};
  floatx4 acc[4][2];
#pragma unroll
  for (int a = 0; a < 4; a++)
#pragma unroll
    for (int b = 0; b < 2; b++) acc[a][b] = zero4;

  for (int kb = 0; kb < (F_DIM / 4) / 32; kb++) {
    gld_lds16(aP0, ldsA0);
    gld_lds16(aP1, ldsA1);
    gld_lds16(bP, ldsB);
    aP0 += 32; aP1 += 32; bP += 32;
    __syncthreads();
    const short* As = smem;
    const short* Bs = smem + 4096;
    short8 af[4], bf[2];
#pragma unroll
    for (int f = 0; f < 4; f++)
      af[f] = *(const short8*)&As[(wm * 64 + f * 16 + r16) * 32 + q * 8];
#pragma unroll
    for (int f = 0; f < 2; f++)
      bf[f] = *(const short8*)&Bs[(wn * 32 + f * 16 + r16) * 32 + q * 8];
#pragma unroll
    for (int fm = 0; fm < 4; fm++)
#pragma unroll
      for (int fn = 0; fn < 2; fn++)
        acc[fm][fn] = __builtin_amdgcn_mfma_f32_16x16x32_bf16(af[fm], bf[fn], acc[fm][fn], 0, 0, 0);
    __syncthreads();
  }

#pragma unroll
  for (int fm = 0; fm < 4; fm++) {
#pragma unroll
    for (int reg = 0; reg < 4; reg++) {
      int row = wm * 64 + fm * 16 + q * 4 + reg;
      int i = mt * 128 + row;
      if (i < n_e) {
        int sid = s_sid[row];
        float wgt = s_w[row];
        float* yp = Y + ((size_t)sk * (T_TOK * 2) + sid) * D_DIM + nt * 64 + wn * 32 + r16;
#pragma unroll
        for (int fn = 0; fn < 2; fn++)
          yp[fn * 16] = acc[fm][fn][reg] * wgt;
      }
    }
  }
}

// ---------------- Combine: out[t] = sum over sk, k of Y4[sk][2t+k] ----------------
__global__ __launch_bounds__(256) void combine_kernel(
    const float* __restrict__ Y, float* __restrict__ out) {
  int idx = blockIdx.x * 256 + threadIdx.x;   // float4 index over T*D/4
  int t = idx >> 8;
  int j = idx & 255;
  const floatx4* Yv = (const floatx4*)Y;
  floatx4 s = {0.f, 0.f, 0.f, 0.f};
#pragma unroll
  for (int sk = 0; sk < 4; sk++) {
    s += Yv[((size_t)sk * (T_TOK * 2) + 2 * t) * 256 + j];
    s += Yv[((size_t)sk * (T_TOK * 2) + 2 * t + 1) * 256 + j];
  }
  ((floatx4*)out)[idx] = s;
}

extern "C" void kernel_launch(void* const* d_in, const int* in_sizes, int n_in,
                              void* d_out, int out_size, void* d_ws, size_t ws_size,
                              hipStream_t stream) {
  const float* x  = (const float*)d_in[0];
  const float* wr = (const float*)d_in[1];
  const float* Wg = (const float*)d_in[2];
  const float* Wu = (const float*)d_in[3];
  const float* Wd = (const float*)d_in[4];
  float* out = (float*)d_out;

  char* ws = (char*)d_ws;
  int*   counts   = (int*)(ws);                          // 32 B
  int*   slot_sid = (int*)(ws + 4096);                   // 64 KB
  float* slot_w   = (float*)(ws + 4096 + 65536);         // 64 KB
  short* Xb       = (short*)(ws + 0x40000);              // 4 MB
  short* H        = (short*)(ws + 0x800000);             // 32 MB
  short* WgT      = (short*)(ws + 0x2800000);            // 64 MB (later: WdT)
  short* WuT      = (short*)(ws + 0x6800000);            // 64 MB (later: Y4)
  short* WdT      = WgT;                                 // reuse after gateup
  float* Y4       = (float*)WuT;                         // reuse after gateup

  hipMemsetAsync(counts, 0, E_NUM * sizeof(int), stream);
  router_kernel<<<T_TOK / 4, 256, 0, stream>>>(x, wr, counts, slot_sid, slot_w);
  cvt_x_kernel<<<T_TOK * D_DIM / 4 / 256, 256, 0, stream>>>(x, Xb);
  // WgT/WuT: [E][D][F] fp32 -> [E][F][D] bf16
  transpose_cvt_kernel<<<dim3(F_DIM / 64, D_DIM / 64, E_NUM), 256, 0, stream>>>(Wg, WgT, D_DIM, F_DIM);
  transpose_cvt_kernel<<<dim3(F_DIM / 64, D_DIM / 64, E_NUM), 256, 0, stream>>>(Wu, WuT, D_DIM, F_DIM);
  gateup_kernel<<<16 * E_NUM * 64, 256, 0, stream>>>(Xb, WgT, WuT, counts, slot_sid, H);
  // WdT: [E][F][D] fp32 -> [E][D][F] bf16 (overwrites WgT region — gateup done)
  transpose_cvt_kernel<<<dim3(D_DIM / 64, F_DIM / 64, E_NUM), 256, 0, stream>>>(Wd, WdT, F_DIM, D_DIM);
  down_kernel<<<16 * E_NUM * 4 * 16, 256, 0, stream>>>(H, WdT, counts, slot_sid, slot_w, Y4);
  combine_kernel<<<T_TOK * D_DIM / 4 / 256, 256, 0, stream>>>(Y4, out);
}

// Round 4
// 643.831 us; speedup vs baseline: 1.0557x; 1.0557x over previous
//
#include <hip/hip_runtime.h>
#include <hip/hip_bf16.h>
#include <math.h>

#define T_TOK 2048
#define D_DIM 1024
#define F_DIM 4096
#define E_NUM 8
#define MAX_TILES 48

typedef __attribute__((ext_vector_type(8))) short short8;
typedef __attribute__((ext_vector_type(4))) short short4v;
typedef __attribute__((ext_vector_type(4))) float floatx4;

__device__ __forceinline__ short f2bf(float f) {
  union { float f; unsigned u; } v; v.f = f;
  unsigned r = v.u + 0x7fffu + ((v.u >> 16) & 1u);  // RNE
  return (short)(r >> 16);
}

// async global->LDS, 16B per lane. LDS base must be wave-uniform; data for
// lane l lands at lds + l*16 bytes.
__device__ __forceinline__ void gld_lds16(const void* g, void* l) {
  __builtin_amdgcn_global_load_lds(
      (const __attribute__((address_space(1))) unsigned int*)g,
      (__attribute__((address_space(3))) unsigned int*)l, 16, 0, 0);
}

// ---------------- Router (fp32): logits, top-2, renorm, expert slot lists ----------------
__global__ __launch_bounds__(256) void router_kernel(
    const float* __restrict__ x, const float* __restrict__ wr,
    int* __restrict__ counts, int* __restrict__ slot_sid, float* __restrict__ slot_w) {
  int lane = threadIdx.x & 63;
  int wave = threadIdx.x >> 6;
  int t = blockIdx.x * 4 + wave;
  const float* xr = x + (size_t)t * D_DIM;
  float acc[8];
#pragma unroll
  for (int e = 0; e < 8; e++) acc[e] = 0.f;
#pragma unroll
  for (int i = 0; i < 16; i++) {
    int d = i * 64 + lane;
    float xv = xr[d];
    const float* w = wr + d * 8;
    float4 w0 = *(const float4*)(w);
    float4 w1 = *(const float4*)(w + 4);
    acc[0] += xv * w0.x; acc[1] += xv * w0.y;
    acc[2] += xv * w0.z; acc[3] += xv * w0.w;
    acc[4] += xv * w1.x; acc[5] += xv * w1.y;
    acc[6] += xv * w1.z; acc[7] += xv * w1.w;
  }
#pragma unroll
  for (int off = 32; off > 0; off >>= 1) {
#pragma unroll
    for (int e = 0; e < 8; e++) acc[e] += __shfl_xor(acc[e], off, 64);
  }
  if (lane == 0) {
    int e1 = 0; float l1 = acc[0];
#pragma unroll
    for (int e = 1; e < 8; e++) { if (acc[e] > l1) { l1 = acc[e]; e1 = e; } }
    int e2 = -1; float l2 = -3.4e38f;
#pragma unroll
    for (int e = 0; e < 8; e++) { if (e != e1 && acc[e] > l2) { l2 = acc[e]; e2 = e; } }
    float w1 = 1.f / (1.f + __expf(l2 - l1));  // softmax->top2->renorm
    float w2 = 1.f - w1;
    int p1 = atomicAdd(&counts[e1], 1);
    slot_sid[e1 * T_TOK + p1] = 2 * t;
    slot_w[e1 * T_TOK + p1] = w1;
    int p2 = atomicAdd(&counts[e2], 1);
    slot_sid[e2 * T_TOK + p2] = 2 * t + 1;
    slot_w[e2 * T_TOK + p2] = w2;
  }
}

// ---------------- Schedule: compact live (e, mt) tile list ----------------
// Live m-tiles (mt < ceil(n_e/128)) become one contiguous prefix of the tile
// array -> GEMM grids are dense (uniform XCD fill) AND same-(e,nt) m-tiles sit
// exactly 64 bids apart (same XCD under bid%8 round-robin) for weight-panel
// L2 reuse. R3 lost 3x FETCH by separating them 512 apart.
__global__ __launch_bounds__(64) void schedule_kernel(
    const int* __restrict__ counts, int* __restrict__ tiles) {
  if (threadIdx.x == 0) {
    int n = 0;
    for (int e = 0; e < E_NUM; e++) {
      int nt_ = (counts[e] + 127) >> 7;
      for (int m = 0; m < nt_; m++) tiles[n++] = (e << 8) | m;
    }
    for (int i = n; i < MAX_TILES; i++) tiles[i] = -1;
  }
}

// ---------------- x fp32 -> bf16 ----------------
__global__ __launch_bounds__(256) void cvt_x_kernel(const float* __restrict__ x,
                                                    short* __restrict__ Xb) {
  int i = blockIdx.x * 256 + threadIdx.x;   // float4 index
  float4 v = ((const float4*)x)[i];
  short4v s;
  s[0] = f2bf(v.x); s[1] = f2bf(v.y); s[2] = f2bf(v.z); s[3] = f2bf(v.w);
  ((short4v*)Xb)[i] = s;
}

// ---------------- Transpose+convert: src fp32 [R][C] -> dst bf16 [C][R] per plane ----------------
// v2 (R4): 128x64 tiles. LDS holds the tile PRE-TRANSPOSED [c][r] with XOR
// swizzle on the r>>3 index (keeps 16B alignment; write-phase conflicts <=4-way)
// so the store side is ds_read_b128 + 256B-contiguous global writes (16 lanes x
// short8 per column). Old version wrote 128B segments + scalar ds_read_u16 and
// ran at ~1.8 TB/s.
__global__ __launch_bounds__(256) void transpose_cvt_kernel(
    const float* __restrict__ src, short* __restrict__ dst, int R, int C) {
  __shared__ short tileT[64 * 128];    // [c][r], swizzled, 16KB
  int cb = blockIdx.x * 64, rb = blockIdx.y * 128;
  size_t plane = (size_t)blockIdx.z * R * C;
  src += plane; dst += plane;
  int tid = threadIdx.x;
  int r0 = tid >> 4, c4 = (tid & 15) * 4;
#pragma unroll
  for (int i = 0; i < 8; i++) {
    int r = r0 + i * 16;
    float4 v = *(const float4*)&src[(size_t)(rb + r) * C + cb + c4];
    int rhw = ((r >> 3) << 3);  // r8-block base
    int rlo = r & 7;
    tileT[(c4 + 0) * 128 + (((r >> 3) ^ ((c4 + 0) & 15)) << 3) + rlo] = f2bf(v.x);
    tileT[(c4 + 1) * 128 + (((r >> 3) ^ ((c4 + 1) & 15)) << 3) + rlo] = f2bf(v.y);
    tileT[(c4 + 2) * 128 + (((r >> 3) ^ ((c4 + 2) & 15)) << 3) + rlo] = f2bf(v.z);
    tileT[(c4 + 3) * 128 + (((r >> 3) ^ ((c4 + 3) & 15)) << 3) + rlo] = f2bf(v.w);
    (void)rhw;
  }
  __syncthreads();
  int c0 = tid >> 4, rq = tid & 15;    // rq = r8>>3
#pragma unroll
  for (int i = 0; i < 4; i++) {
    int c = c0 + i * 16;
    short8 s = *(const short8*)&tileT[c * 128 + ((rq ^ (c & 15)) << 3)];
    *(short8*)&dst[(size_t)(cb + c) * R + rb + rq * 8] = s;
  }
}

// ---------------- Fused gate+up GEMM: tile 128x64, BK=32, single-buffer ----------------
// grid = MAX_TILES*64; bid = tile*64 + nt; tile list from schedule_kernel.
// launch_bounds (256,4): R3 compiled to 64 VGPR + 64 acc = 128 unified ->
// 4 waves/SIMD fits; the (256,3) bound was the binding occupancy cap.
__global__ __launch_bounds__(256, 4) void gateup_kernel(
    const short* __restrict__ Xb, const short* __restrict__ WgT, const short* __restrict__ WuT,
    const int* __restrict__ counts, const int* __restrict__ slot_sid,
    const int* __restrict__ tiles, short* __restrict__ H) {
  __shared__ short smem[8192];         // As 128x32 (4K shorts) | Bg 64x32 (2K) | Bu 64x32 (2K)
  __shared__ int s_sid[128];

  int bid = blockIdx.x;
  int tile = tiles[bid >> 6];
  if (tile < 0) return;
  int e  = tile >> 8;
  int mt = tile & 255;
  int nt = bid & 63;
  int n_e = counts[e];

  int tid = threadIdx.x;
  if (tid < 128) {
    int i = mt * 128 + tid;
    if (i > n_e - 1) i = n_e - 1;      // clamp; guarded at store
    s_sid[tid] = slot_sid[e * T_TOK + i];
  }
  __syncthreads();

  int lane = tid & 63;
  int w = tid >> 6;
  int wm = w >> 1, wn = w & 1;
  int r16 = lane & 15, q = lane >> 4;

  // staging: A rows in 2 chunks of 16/wave (rows w*16+r, 64+w*16+r); B rows w*16+r
  int rl = lane >> 2;                  // row within 16-chunk
  int kc = (lane & 3) * 8;             // shorts within 32-k row
  const short* aP0 = Xb + (size_t)(s_sid[w * 16 + rl] >> 1) * D_DIM + kc;
  const short* aP1 = Xb + (size_t)(s_sid[64 + w * 16 + rl] >> 1) * D_DIM + kc;
  size_t wbase = (size_t)e * F_DIM * D_DIM + (size_t)(nt * 64 + w * 16 + rl) * D_DIM;
  const short* gP = WgT + wbase + kc;
  const short* uP = WuT + wbase + kc;
  short* ldsA0 = smem + w * 512;               // rows [w*16,w*16+16)
  short* ldsA1 = smem + 2048 + w * 512;        // rows [64+w*16, ...)
  short* ldsBg = smem + 4096 + w * 512;
  short* ldsBu = smem + 6144 + w * 512;

  floatx4 zero4 = {0.f, 0.f, 0.f, 0.f};
  floatx4 accg[4][2], accu[4][2];
#pragma unroll
  for (int a = 0; a < 4; a++)
#pragma unroll
    for (int b = 0; b < 2; b++) { accg[a][b] = zero4; accu[a][b] = zero4; }

  for (int kb = 0; kb < D_DIM / 32; kb++) {
    gld_lds16(aP0, ldsA0);
    gld_lds16(aP1, ldsA1);
    gld_lds16(gP, ldsBg);
    gld_lds16(uP, ldsBu);
    aP0 += 32; aP1 += 32; gP += 32; uP += 32;
    __syncthreads();
    const short* As = smem;
    const short* Bg = smem + 4096;
    const short* Bu = smem + 6144;
    short8 af[4], bgf[2], buf_[2];
#pragma unroll
    for (int f = 0; f < 4; f++)
      af[f] = *(const short8*)&As[(wm * 64 + f * 16 + r16) * 32 + q * 8];
#pragma unroll
    for (int f = 0; f < 2; f++) {
      bgf[f]  = *(const short8*)&Bg[(wn * 32 + f * 16 + r16) * 32 + q * 8];
      buf_[f] = *(const short8*)&Bu[(wn * 32 + f * 16 + r16) * 32 + q * 8];
    }
#pragma unroll
    for (int fm = 0; fm < 4; fm++)
#pragma unroll
      for (int fn = 0; fn < 2; fn++) {
        accg[fm][fn] = __builtin_amdgcn_mfma_f32_16x16x32_bf16(af[fm], bgf[fn],  accg[fm][fn], 0, 0, 0);
        accu[fm][fn] = __builtin_amdgcn_mfma_f32_16x16x32_bf16(af[fm], buf_[fn], accu[fm][fn], 0, 0, 0);
      }
    __syncthreads();
  }

  // epilogue via LDS slab (stride 72 shorts = 144B, 16B-aligned rows) -> 16B stores
  short* slab = smem;
#pragma unroll
  for (int fm = 0; fm < 4; fm++) {
#pragma unroll
    for (int reg = 0; reg < 4; reg++) {
      int rowl = wm * 16 + q * 4 + reg;
#pragma unroll
      for (int fn = 0; fn < 2; fn++) {
        float g = accg[fm][fn][reg];
        float u = accu[fm][fn][reg];
        float h = g * u / (1.f + __expf(-g));
        slab[rowl * 72 + wn * 32 + fn * 16 + r16] = f2bf(h);
      }
    }
    __syncthreads();
    int rr = tid >> 3, cs = (tid & 7) * 8;     // 32 rows x 64 shorts, 16B/thread
    int grow = (rr >> 4) * 64 + fm * 16 + (rr & 15);
    if (mt * 128 + grow < n_e) {
      int sid = s_sid[grow];
      short8 v0 = *(const short8*)&slab[rr * 72 + cs];
      *(short8*)(H + (size_t)sid * F_DIM + nt * 64 + cs) = v0;
    }
    __syncthreads();
  }
}

// ---------------- Down GEMM, split-K=4: tile 128x64, BK=32, single-buffer ----------------
// grid = MAX_TILES*64; bid = tile*64 + sk*16 + nt.
__global__ __launch_bounds__(256, 4) void down_kernel(
    const short* __restrict__ H, const short* __restrict__ WdT,
    const int* __restrict__ counts, const int* __restrict__ slot_sid,
    const float* __restrict__ slot_w, const int* __restrict__ tiles,
    float* __restrict__ Y) {
  __shared__ short smem[6144];         // As 128x32 (4K shorts) | Bs 64x32 (2K)
  __shared__ int s_sid[128];
  __shared__ float s_w[128];

  int bid = blockIdx.x;
  int tile = tiles[bid >> 6];
  if (tile < 0) return;
  int e  = tile >> 8;
  int mt = tile & 255;
  int sk = (bid >> 4) & 3;
  int nt = bid & 15;
  int n_e = counts[e];

  int tid = threadIdx.x;
  if (tid < 128) {
    int i = mt * 128 + tid;
    if (i > n_e - 1) i = n_e - 1;
    s_sid[tid] = slot_sid[e * T_TOK + i];
    s_w[tid]   = slot_w[e * T_TOK + i];
  }
  __syncthreads();

  int lane = tid & 63;
  int w = tid >> 6;
  int wm = w >> 1, wn = w & 1;
  int r16 = lane & 15, q = lane >> 4;

  int rl = lane >> 2;
  int kc = (lane & 3) * 8;
  int ks = sk * (F_DIM / 4);
  const short* aP0 = H + (size_t)s_sid[w * 16 + rl] * F_DIM + ks + kc;
  const short* aP1 = H + (size_t)s_sid[64 + w * 16 + rl] * F_DIM + ks + kc;
  const short* bP = WdT + ((size_t)e * D_DIM + nt * 64 + w * 16 + rl) * F_DIM + ks + kc;
  short* ldsA0 = smem + w * 512;
  short* ldsA1 = smem + 2048 + w * 512;
  short* ldsB  = smem + 4096 + w * 512;

  floatx4 zero4 = {0.f, 0.f, 0.f, 0.f};
  floatx4 acc[4][2];
#pragma unroll
  for (int a = 0; a < 4; a++)
#pragma unroll
    for (int b = 0; b < 2; b++) acc[a][b] = zero4;

  for (int kb = 0; kb < (F_DIM / 4) / 32; kb++) {
    gld_lds16(aP0, ldsA0);
    gld_lds16(aP1, ldsA1);
    gld_lds16(bP, ldsB);
    aP0 += 32; aP1 += 32; bP += 32;
    __syncthreads();
    const short* As = smem;
    const short* Bs = smem + 4096;
    short8 af[4], bf[2];
#pragma unroll
    for (int f = 0; f < 4; f++)
      af[f] = *(const short8*)&As[(wm * 64 + f * 16 + r16) * 32 + q * 8];
#pragma unroll
    for (int f = 0; f < 2; f++)
      bf[f] = *(const short8*)&Bs[(wn * 32 + f * 16 + r16) * 32 + q * 8];
#pragma unroll
    for (int fm = 0; fm < 4; fm++)
#pragma unroll
      for (int fn = 0; fn < 2; fn++)
        acc[fm][fn] = __builtin_amdgcn_mfma_f32_16x16x32_bf16(af[fm], bf[fn], acc[fm][fn], 0, 0, 0);
    __syncthreads();
  }

#pragma unroll
  for (int fm = 0; fm < 4; fm++) {
#pragma unroll
    for (int reg = 0; reg < 4; reg++) {
      int row = wm * 64 + fm * 16 + q * 4 + reg;
      int i = mt * 128 + row;
      if (i < n_e) {
        int sid = s_sid[row];
        float wgt = s_w[row];
        float* yp = Y + ((size_t)sk * (T_TOK * 2) + sid) * D_DIM + nt * 64 + wn * 32 + r16;
#pragma unroll
        for (int fn = 0; fn < 2; fn++)
          yp[fn * 16] = acc[fm][fn][reg] * wgt;
      }
    }
  }
}

// ---------------- Combine: out[t] = sum over sk, k of Y4[sk][2t+k] ----------------
__global__ __launch_bounds__(256) void combine_kernel(
    const float* __restrict__ Y, float* __restrict__ out) {
  int idx = blockIdx.x * 256 + threadIdx.x;   // float4 index over T*D/4
  int t = idx >> 8;
  int j = idx & 255;
  const floatx4* Yv = (const floatx4*)Y;
  floatx4 s = {0.f, 0.f, 0.f, 0.f};
#pragma unroll
  for (int sk = 0; sk < 4; sk++) {
    s += Yv[((size_t)sk * (T_TOK * 2) + 2 * t) * 256 + j];
    s += Yv[((size_t)sk * (T_TOK * 2) + 2 * t + 1) * 256 + j];
  }
  ((floatx4*)out)[idx] = s;
}

extern "C" void kernel_launch(void* const* d_in, const int* in_sizes, int n_in,
                              void* d_out, int out_size, void* d_ws, size_t ws_size,
                              hipStream_t stream) {
  const float* x  = (const float*)d_in[0];
  const float* wr = (const float*)d_in[1];
  const float* Wg = (const float*)d_in[2];
  const float* Wu = (const float*)d_in[3];
  const float* Wd = (const float*)d_in[4];
  float* out = (float*)d_out;

  char* ws = (char*)d_ws;
  int*   counts   = (int*)(ws);                          // 32 B
  int*   tiles    = (int*)(ws + 2048);                   // 192 B
  int*   slot_sid = (int*)(ws + 4096);                   // 64 KB
  float* slot_w   = (float*)(ws + 4096 + 65536);         // 64 KB
  short* Xb       = (short*)(ws + 0x40000);              // 4 MB
  short* H        = (short*)(ws + 0x800000);             // 32 MB
  short* WgT      = (short*)(ws + 0x2800000);            // 64 MB (later: WdT)
  short* WuT      = (short*)(ws + 0x6800000);            // 64 MB (later: Y4)
  short* WdT      = WgT;                                 // reuse after gateup
  float* Y4       = (float*)WuT;                         // reuse after gateup

  hipMemsetAsync(counts, 0, E_NUM * sizeof(int), stream);
  router_kernel<<<T_TOK / 4, 256, 0, stream>>>(x, wr, counts, slot_sid, slot_w);
  schedule_kernel<<<1, 64, 0, stream>>>(counts, tiles);
  cvt_x_kernel<<<T_TOK * D_DIM / 4 / 256, 256, 0, stream>>>(x, Xb);
  // WgT/WuT: [E][D][F] fp32 -> [E][F][D] bf16
  transpose_cvt_kernel<<<dim3(F_DIM / 64, D_DIM / 128, E_NUM), 256, 0, stream>>>(Wg, WgT, D_DIM, F_DIM);
  transpose_cvt_kernel<<<dim3(F_DIM / 64, D_DIM / 128, E_NUM), 256, 0, stream>>>(Wu, WuT, D_DIM, F_DIM);
  gateup_kernel<<<MAX_TILES * 64, 256, 0, stream>>>(Xb, WgT, WuT, counts, slot_sid, tiles, H);
  // WdT: [E][F][D] fp32 -> [E][D][F] bf16 (overwrites WgT region — gateup done)
  transpose_cvt_kernel<<<dim3(D_DIM / 64, F_DIM / 128, E_NUM), 256, 0, stream>>>(Wd, WdT, F_DIM, D_DIM);
  down_kernel<<<MAX_TILES * 64, 256, 0, stream>>>(H, WdT, counts, slot_sid, slot_w, tiles, Y4);
  combine_kernel<<<T_TOK * D_DIM / 4 / 256, 256, 0, stream>>>(Y4, out);
}